// Round 11
// baseline (680.999 us; speedup 1.0000x reference)
//
#include <hip/hip_runtime.h>

#define M_DIM 65536
#define K_DIM 2048
#define N_DIM 1024
#define EPSV 1e-5f

typedef __bf16 bf16;
typedef bf16 bf16x8 __attribute__((ext_vector_type(8)));
typedef bf16 bf16x4 __attribute__((ext_vector_type(4)));
typedef float f32x4 __attribute__((ext_vector_type(4)));

// monotone float <-> uint encoding for atomicMin on float
__device__ inline unsigned fenc(float f) {
    unsigned u = __float_as_uint(f);
    return (u & 0x80000000u) ? ~u : (u | 0x80000000u);
}
__device__ inline float fdec(unsigned e) {
    unsigned u = (e & 0x80000000u) ? (e & 0x7fffffffu) : ~e;
    return __uint_as_float(u);
}

__device__ __forceinline__ void gload_lds16(const bf16* g, bf16* l) {
    __builtin_amdgcn_global_load_lds(
        (const __attribute__((address_space(1))) unsigned int*)g,
        (__attribute__((address_space(3))) unsigned int*)l, 16, 0, 0);
}

// fp32 -> bf16 conversion, vectorized
__global__ void cvt_kernel(const float* __restrict__ in, bf16* __restrict__ out, long n4) {
    long i = (long)blockIdx.x * blockDim.x + threadIdx.x;
    long stride = (long)gridDim.x * blockDim.x;
    for (; i < n4; i += stride) {
        float4 v = ((const float4*)in)[i];
        bf16x4 h;
        h[0] = (bf16)v.x; h[1] = (bf16)v.y; h[2] = (bf16)v.z; h[3] = (bf16)v.w;
        ((bf16x4*)out)[i] = h;
    }
}

// A staging: one [256 rows][32 k] bf16 half-tile (16 KB): 512 threads x 2
// global_load_lds(16B). LDS dest LINEAR; XOR swizzle (granule ^= (row>>1)&3)
// on the GLOBAL source (both-sides involution). Conflict-free (R2: 0).
__device__ __forceinline__ void stage_half(const bf16* __restrict__ g0, int kbase,
                                           bf16* slot, int tid) {
#pragma unroll
    for (int i = 0; i < 2; ++i) {
        int gidx = i * 512 + tid;           // 16B granule id, 1024 per half-tile
        int row = gidx >> 2;                // 4 granules (64B) per row
        int gsw = (gidx & 3) ^ ((row >> 1) & 3);
        gload_lds16(g0 + (size_t)row * K_DIM + kbase + gsw * 8,
                    slot + (size_t)(i * 512 + (tid & 448)) * 8);  // wave-uniform base
    }
}

// LDS: A ONLY — 4 slots [parity][khalf] of [256][32] bf16 = 64 KiB total.
// B is loaded global->register (W = 4 MB, resident in every XCD L2).
#define ASL(P, H) (lds + ((P) * 2 + (H)) * 8192)

// 256x256 tile, BK=64 as two K-halves; 8 waves (2Mx4N), per-wave 128x64
// (8x4 frags of 16x16x32), R4's 8-thin-phase loop. CHANGE (AITER s02
// pattern): B-fragments come straight from global into a double register
// buffer (bA/bB), issued 2 phases ahead; A keeps the proven gload_lds path.
// DS traffic drops 40% (reads 48->32, writes 12->8 per iter-lane); B's
// 2340 L2-cyc/iter ride the VMEM pipe, overlapping DS+MFMA.
//
// FIFO ledger (batches; A-stage=2 loads, B-issue=4): issue order per even
// phase = [ds-reads][A-stage][B-issue][MFMA]. The compiler's wait on the
// B-buffer before each MFMA cluster (vmcnt(6): allows the 6 loads newer
// than that B batch) force-completes every older A-stage at >=2-phase age
// (~2600 cyc >> 900 HBM) — never a stall. Steady in-flight at even-phase
// tops = 6 (A-stage(2)+B-issue(4) of the previous even phase), so the
// GATE vmcnt(8) is a free fence; at iter-0 P0 it drains exactly the
// prologue's A(0,0) batch (10 in flight -> 8). One ~900cyc stall total
// (prologue B wait).
__global__ __launch_bounds__(512, 2)
void gemm_fused(const bf16* __restrict__ Xb, const bf16* __restrict__ Wb,
                const float* __restrict__ gnw, const float* __restrict__ gnb,
                unsigned* __restrict__ rowmin) {
    extern __shared__ __align__(16) bf16 lds[];  // 64 KiB dynamic

    const int tid = threadIdx.x;
    const int wave = tid >> 6, lane = tid & 63;
    const int wr = wave >> 2, wc = wave & 3;     // 2 x 4 wave grid
    const int q = lane >> 4, r = lane & 15;

    // T1: bijective XCD-chunked block swizzle (1024 blocks % 8 == 0)
    const int bid = blockIdx.x;
    const int swz = (bid & 7) * 128 + (bid >> 3);
    const int bx = swz & 3, by = swz >> 2;
    const int brow = by * 256, bcol = bx * 256;

    const bf16* Arow = Xb + (size_t)brow * K_DIM;
    // B-frag base: lane (q,r), frag n, kbase kb -> W[bcol+wc*64+n*16+r][kb+q*8]
    const bf16* Bb = Wb + (size_t)(bcol + wc * 64 + r) * K_DIM + q * 8;

    // per-lane LDS read offset for A (bf16 units); swizzle term == (r>>1)&3
    const int gswr = (r >> 1) & 3;
    const int aoff = (wr * 128 + r) * 32 + (q ^ gswr) * 8;

    f32x4 acc[8][4];
#pragma unroll
    for (int m = 0; m < 8; ++m)
#pragma unroll
        for (int n = 0; n < 4; ++n) acc[m][n] = 0.0f;

    bf16x8 af[4], bA[4], bB[4];

#define GATE do {                                                 \
        asm volatile("s_waitcnt vmcnt(8)" ::: "memory");          \
        __builtin_amdgcn_s_barrier();                             \
        asm volatile("" ::: "memory");                            \
    } while (0)

#define READ_A(P, H, MH) {                                                        \
        _Pragma("unroll") for (int m = 0; m < 4; ++m)                             \
            af[m] = *(const bf16x8*)(ASL(P, H) + aoff + ((MH) * 4 + m) * 512);    \
    }

    // 4 x global_load_dwordx4 into a named reg buffer; clobber pins the
    // issue position (prevents sinking past the MFMA cluster)
#define B_ISSUE(DST, KB) do {                                                     \
        _Pragma("unroll") for (int n = 0; n < 4; ++n)                             \
            DST[n] = *(const bf16x8*)(Bb + (size_t)(n * 16) * K_DIM + (KB));      \
        asm volatile("" ::: "memory");                                            \
    } while (0)

#define MFMA_PH(MH, BBUF) do {                                                    \
        __builtin_amdgcn_s_barrier();                                             \
        __builtin_amdgcn_s_setprio(1);                                            \
        _Pragma("unroll") for (int m = 0; m < 4; ++m)                             \
            _Pragma("unroll") for (int n = 0; n < 4; ++n)                         \
                acc[(MH) * 4 + m][n] = __builtin_amdgcn_mfma_f32_16x16x32_bf16(   \
                    af[m], BBUF[n], acc[(MH) * 4 + m][n], 0, 0, 0);               \
        __builtin_amdgcn_s_setprio(0);                                            \
        __builtin_amdgcn_s_barrier();                                             \
    } while (0)

    // ---- prologue: A(0,0),(0,1),(1,0) staged (6 loads); bA <- tile0 kh0 ----
    stage_half(Arow, 0,  ASL(0, 0), tid);
    stage_half(Arow, 32, ASL(0, 1), tid);
    stage_half(Arow, 64, ASL(1, 0), tid);
    B_ISSUE(bA, 0);

    // ---- main loop: 16 iterations x 2 K-tiles (K=2048, BK=64) ----
    // Consumption: P0/P1 A(0,0)+bA(2i,kh0); P2/P3 A(0,1)+bB(2i,kh1);
    //              P4/P5 A(1,0)+bA(2i+1,kh0); P6/P7 A(1,1)+bB(2i+1,kh1).
    // Stages (A): P0->slot(1,1)@(2i+1)kh1; P2->(0,0)@t2 kh0;
    //             P4->(0,1)@t2 kh1; P6->(1,0)@t3 kh0.
    // Issues (B): P0->bB@(2i)kh1; P2->bA@(2i+1)kh0; P4->bB@(2i+1)kh1;
    //             P6->bA@t2 kh0 (next-iter P0).
    for (int i = 0; i < 16; ++i) {
        const int k0 = 2 * i * 64, k1 = (2 * i + 1) * 64;
        const int t2 = (2 * i + 2) & 31, t3 = (2 * i + 3) & 31;  // wrap: never read
        // P0
        GATE;
        READ_A(0, 0, 0);
        stage_half(Arow, k1 + 32, ASL(1, 1), tid);
        B_ISSUE(bB, k0 + 32);
        MFMA_PH(0, bA);
        // P1
        READ_A(0, 0, 1);
        MFMA_PH(1, bA);
        // P2
        GATE;
        READ_A(0, 1, 0);
        stage_half(Arow, t2 * 64, ASL(0, 0), tid);
        B_ISSUE(bA, k1);
        MFMA_PH(0, bB);
        // P3
        READ_A(0, 1, 1);
        MFMA_PH(1, bB);
        // P4
        GATE;
        READ_A(1, 0, 0);
        stage_half(Arow, t2 * 64 + 32, ASL(0, 1), tid);
        B_ISSUE(bB, k1 + 32);
        MFMA_PH(0, bA);
        // P5
        READ_A(1, 0, 1);
        MFMA_PH(1, bA);
        // P6
        GATE;
        READ_A(1, 1, 0);
        stage_half(Arow, t3 * 64, ASL(1, 0), tid);
        B_ISSUE(bA, t2 * 64);
        MFMA_PH(0, bB);
        // P7
        READ_A(1, 1, 1);
        MFMA_PH(1, bB);
    }

    // ---- fused epilogue: GroupNorm (group == wave's 64-col span) + row min ----
    float gw[4], gb[4];
#pragma unroll
    for (int n = 0; n < 4; ++n) {
        int col = bcol + wc * 64 + n * 16 + r;
        gw[n] = gnw[col];
        gb[n] = gnb[col];
    }
#pragma unroll
    for (int m = 0; m < 8; ++m) {
#pragma unroll
        for (int j = 0; j < 4; ++j) {
            float s = 0.f, ss = 0.f;
#pragma unroll
            for (int n = 0; n < 4; ++n) {
                float v = acc[m][n][j];
                s += v; ss += v * v;
            }
#pragma unroll
            for (int d = 1; d < 16; d <<= 1) {
                s += __shfl_xor(s, d);
                ss += __shfl_xor(ss, d);
            }
            float mean = s * (1.f / 64.f);
            float var = ss * (1.f / 64.f) - mean * mean;
            float rstd = rsqrtf(var + EPSV);
            float mn = 3.4e38f;
#pragma unroll
            for (int n = 0; n < 4; ++n) {
                float y = (acc[m][n][j] - mean) * rstd * gw[n] + gb[n];
                mn = fminf(mn, y);
            }
#pragma unroll
            for (int d = 1; d < 16; d <<= 1) mn = fminf(mn, __shfl_xor(mn, d));
            if (r == 0)
                atomicMin(&rowmin[brow + wr * 128 + m * 16 + q * 4 + j], fenc(mn));
        }
    }
}

// out[m][n] = dec(rowmin[m]) + bias[n]
__global__ void bcast_kernel(const unsigned* __restrict__ rowmin,
                             const float* __restrict__ bias,
                             float* __restrict__ out) {
    const long total4 = (long)M_DIM * N_DIM / 4;
    long i = (long)blockIdx.x * blockDim.x + threadIdx.x;
    long stride = (long)gridDim.x * blockDim.x;
    for (; i < total4; i += stride) {
        int mrow = (int)(i >> 8);  // N/4 = 256 float4 per row
        int n4 = (int)(i & 255);
        float rm = fdec(rowmin[mrow]);
        float4 b = ((const float4*)bias)[n4];
        float4 o;
        o.x = rm + b.x; o.y = rm + b.y; o.z = rm + b.z; o.w = rm + b.w;
        ((float4*)out)[i] = o;
    }
}

extern "C" void kernel_launch(void* const* d_in, const int* in_sizes, int n_in,
                              void* d_out, int out_size, void* d_ws, size_t ws_size,
                              hipStream_t stream) {
    const float* x = (const float*)d_in[0];
    const float* w = (const float*)d_in[1];
    const float* gnw = (const float*)d_in[2];
    const float* gnb = (const float*)d_in[3];
    const float* bias = (const float*)d_in[4];

    unsigned char* ws = (unsigned char*)d_ws;
    unsigned* rowmin = (unsigned*)ws;                          // 256 KB
    bf16* wb = (bf16*)(ws + (size_t)M_DIM * 4);                // 4 MB
    bf16* xb = (bf16*)(ws + (size_t)M_DIM * 4 + (size_t)N_DIM * K_DIM * 2);  // 256 MB

    hipFuncSetAttribute((const void*)gemm_fused,
                        hipFuncAttributeMaxDynamicSharedMemorySize, 65536);

    hipMemsetAsync(rowmin, 0xFF, (size_t)M_DIM * 4, stream);   // +inf in encoding
    cvt_kernel<<<512, 256, 0, stream>>>(w, wb, (long)N_DIM * K_DIM / 4);
    cvt_kernel<<<4096, 256, 0, stream>>>(x, xb, (long)M_DIM * K_DIM / 4);

    gemm_fused<<<dim3(1024), 512, 65536, stream>>>(xb, wb, gnw, gnb, rowmin);

    bcast_kernel<<<2048, 256, 0, stream>>>(rowmin, bias, (float*)d_out);
}